// Round 3
// baseline (138.087 us; speedup 1.0000x reference)
//
#include <hip/hip_runtime.h>
#include <math.h>

#define MAXT 2048

__device__ __forceinline__ unsigned keyOf(float f) {
  unsigned b = __float_as_uint(f);
  return b ^ ((b & 0x80000000u) ? 0xFFFFFFFFu : 0x80000000u);
}

__device__ __forceinline__ float waveMax(float v) {
#pragma unroll
  for (int o = 32; o >= 1; o >>= 1) v = fmaxf(v, __shfl_xor(v, o));
  return v;
}
__device__ __forceinline__ float waveSum(float v) {
#pragma unroll
  for (int o = 32; o >= 1; o >>= 1) v += __shfl_xor(v, o);
  return v;
}

// Block-wide: find the bin where the cumulative histogram crosses `rank`.
// res[0] = bin, res[1] = remaining rank within that bin. All 256 threads
// participate; `h` has 256*per bins. Deterministic (pure function of h).
__device__ __forceinline__ void selectStep(const unsigned* __restrict__ h,
                                           int per, unsigned rank,
                                           unsigned* sc, unsigned* res) {
  int t = threadIdx.x;
  unsigned local[8];
  unsigned s = 0;
  for (int j = 0; j < per; ++j) { local[j] = h[t * per + j]; s += local[j]; }
  sc[t] = s;
  __syncthreads();
  for (int off = 1; off < 256; off <<= 1) {
    unsigned v = (t >= off) ? sc[t - off] : 0u;
    __syncthreads();
    sc[t] += v;
    __syncthreads();
  }
  unsigned incl = sc[t], excl = incl - s;
  if (excl < rank && rank <= incl) {
    unsigned cum = excl;
    for (int j = 0; j < per; ++j) {
      if (cum + local[j] >= rank) {
        res[0] = (unsigned)(t * per + j);
        res[1] = rank - cum;
        break;
      }
      cum += local[j];
    }
  }
  __syncthreads();
}

// Zero all histogram buffers + tie counters.
__global__ __launch_bounds__(256) void init_kernel(unsigned* __restrict__ hbase,
                                                   unsigned* __restrict__ tc) {
  int t = threadIdx.x;
  for (int j = t; j < 2 * (2048 + 2048 + 1024); j += 256) hbase[j] = 0u;
  if (t < 2) tc[t] = 0u;
}

// One wave per row, C = 1000 fp32 (250 float4). Pure CE loss: memory-bound,
// no atomics, y[row,t] extracted from registers via one shuffle.
__global__ __launch_bounds__(256) void ce_kernel(
    const float* __restrict__ y1, const float* __restrict__ y2,
    const int* __restrict__ tgt,
    float* __restrict__ l1, float* __restrict__ l2, int N) {
  const float L2E = 1.4426950408889634f;
  const float LN2 = 0.6931471805599453f;
  int wid = threadIdx.x >> 6, lane = threadIdx.x & 63;
  int row = blockIdx.x * 4 + wid;
  if (row >= N) return;
  int t = tgt[row];
  int vecIdx = t >> 2;
  int grp = vecIdx >> 6;
  int srcLane = vecIdx & 63;
  int comp = t & 3;
#pragma unroll
  for (int which = 0; which < 2; ++which) {
    const float* y = which ? y2 : y1;
    const float4* rp = (const float4*)(y + (size_t)row * 1000);
    float4 a = rp[lane];
    float4 b = rp[lane + 64];
    float4 c = rp[lane + 128];
    float4 d = make_float4(-INFINITY, -INFINITY, -INFINITY, -INFINITY);
    if (lane + 192 < 250) d = rp[lane + 192];
    float4 sel = (grp == 0) ? a : (grp == 1) ? b : (grp == 2) ? c : d;
    float cand = (comp == 0) ? sel.x : (comp == 1) ? sel.y
               : (comp == 2) ? sel.z : sel.w;
    float xt = __shfl(cand, srcLane);
    float m = fmaxf(fmaxf(fmaxf(a.x, a.y), fmaxf(a.z, a.w)),
                    fmaxf(fmaxf(b.x, b.y), fmaxf(b.z, b.w)));
    m = fmaxf(m, fmaxf(fmaxf(c.x, c.y), fmaxf(c.z, c.w)));
    m = fmaxf(m, fmaxf(fmaxf(d.x, d.y), fmaxf(d.z, d.w)));
    m = waveMax(m);
    float s = exp2f((a.x - m) * L2E) + exp2f((a.y - m) * L2E) +
              exp2f((a.z - m) * L2E) + exp2f((a.w - m) * L2E) +
              exp2f((b.x - m) * L2E) + exp2f((b.y - m) * L2E) +
              exp2f((b.z - m) * L2E) + exp2f((b.w - m) * L2E) +
              exp2f((c.x - m) * L2E) + exp2f((c.y - m) * L2E) +
              exp2f((c.z - m) * L2E) + exp2f((c.w - m) * L2E) +
              exp2f((d.x - m) * L2E) + exp2f((d.y - m) * L2E) +
              exp2f((d.z - m) * L2E) + exp2f((d.w - m) * L2E);
    s = waveSum(s);
    if (lane == 0) {
      float loss = log2f(s) * LN2 + m - xt;
      (which ? l2 : l1)[row] = loss;
    }
  }
}

// Pass-A histogram (top 11 key bits), LDS-privatized: loss keys concentrate
// in a handful of bins so per-element global atomics would serialize.
__global__ __launch_bounds__(256) void histA_kernel(
    const float* __restrict__ l1, const float* __restrict__ l2,
    unsigned* __restrict__ hA1, unsigned* __restrict__ hA2, int N) {
  __shared__ unsigned lh[2][2048];
  int t = threadIdx.x;
  for (int j = t; j < 2048; j += 256) { lh[0][j] = 0u; lh[1][j] = 0u; }
  __syncthreads();
  for (int i = blockIdx.x * blockDim.x + t; i < N;
       i += gridDim.x * blockDim.x) {
    atomicAdd(&lh[0][keyOf(l1[i]) >> 21], 1u);
    atomicAdd(&lh[1][keyOf(l2[i]) >> 21], 1u);
  }
  __syncthreads();
  for (int j = t; j < 2048; j += 256) {
    unsigned v0 = lh[0][j], v1 = lh[1][j];
    if (v0) atomicAdd(&hA1[j], v0);
    if (v1) atomicAdd(&hA2[j], v1);
  }
}

// Pass B: each block redundantly recomputes the pass-A scan (cheap, pure
// function of the completed hA), then histograms key bits 20..10 of elements
// matching the selected pass-A bin. Mantissa bits -> well-spread atomics.
__global__ __launch_bounds__(256) void histB_kernel(
    const float* __restrict__ l1, const float* __restrict__ l2,
    const unsigned* __restrict__ hA1, const unsigned* __restrict__ hA2,
    unsigned* __restrict__ hB1, unsigned* __restrict__ hB2,
    const int* __restrict__ numKeep, int N) {
  __shared__ unsigned sc[256];
  __shared__ unsigned resA1[2], resA2[2];
  unsigned k0 = (unsigned)(*numKeep);
  selectStep(hA1, 8, k0, sc, resA1);
  selectStep(hA2, 8, k0, sc, resA2);
  unsigned a1 = resA1[0], a2 = resA2[0];
  for (int i = blockIdx.x * blockDim.x + threadIdx.x; i < N;
       i += gridDim.x * blockDim.x) {
    unsigned k1 = keyOf(l1[i]);
    if ((k1 >> 21) == a1) atomicAdd(&hB1[(k1 >> 10) & 2047u], 1u);
    unsigned k2 = keyOf(l2[i]);
    if ((k2 >> 21) == a2) atomicAdd(&hB2[(k2 >> 10) & 2047u], 1u);
  }
}

// Pass C: redundant scans of A and B, then histogram of the low 10 key bits.
__global__ __launch_bounds__(256) void histC_kernel(
    const float* __restrict__ l1, const float* __restrict__ l2,
    const unsigned* __restrict__ hA1, const unsigned* __restrict__ hA2,
    const unsigned* __restrict__ hB1, const unsigned* __restrict__ hB2,
    unsigned* __restrict__ hC1, unsigned* __restrict__ hC2,
    const int* __restrict__ numKeep, int N) {
  __shared__ unsigned sc[256];
  __shared__ unsigned rA1[2], rA2[2], rB1[2], rB2[2];
  unsigned k0 = (unsigned)(*numKeep);
  selectStep(hA1, 8, k0, sc, rA1);
  selectStep(hA2, 8, k0, sc, rA2);
  selectStep(hB1, 8, rA1[1], sc, rB1);
  selectStep(hB2, 8, rA2[1], sc, rB2);
  unsigned p1 = (rA1[0] << 21) | (rB1[0] << 10);
  unsigned p2 = (rA2[0] << 21) | (rB2[0] << 10);
  for (int i = blockIdx.x * blockDim.x + threadIdx.x; i < N;
       i += gridDim.x * blockDim.x) {
    unsigned k1 = keyOf(l1[i]);
    if ((k1 & 0xFFFFFC00u) == p1) atomicAdd(&hC1[k1 & 1023u], 1u);
    unsigned k2 = keyOf(l2[i]);
    if ((k2 & 0xFFFFFC00u) == p2) atomicAdd(&hC2[k2 & 1023u], 1u);
  }
}

// Partial sums + tie collection. Redundant scans A,B,C give the exact k-th
// smallest key K and the remaining rank (= #ties to include). Sums cover
// strictly-smaller keys; tied elements are appended (idx, other-net loss)
// for deterministic resolution in final_kernel. needs[] written redundantly
// with identical values by every block (benign).
__global__ __launch_bounds__(256) void partial_kernel(
    const float* __restrict__ l1, const float* __restrict__ l2,
    const unsigned* __restrict__ hA1, const unsigned* __restrict__ hA2,
    const unsigned* __restrict__ hB1, const unsigned* __restrict__ hB2,
    const unsigned* __restrict__ hC1, const unsigned* __restrict__ hC2,
    const int* __restrict__ numKeep, unsigned* __restrict__ needs,
    unsigned* __restrict__ tc, int* __restrict__ tIdx1, float* __restrict__ tVal1,
    int* __restrict__ tIdx2, float* __restrict__ tVal2,
    float* __restrict__ partials, int N) {
  __shared__ unsigned sc[256];
  __shared__ unsigned rA1[2], rA2[2], rB1[2], rB2[2], rC1[2], rC2[2];
  unsigned k0 = (unsigned)(*numKeep);
  selectStep(hA1, 8, k0, sc, rA1);
  selectStep(hA2, 8, k0, sc, rA2);
  selectStep(hB1, 8, rA1[1], sc, rB1);
  selectStep(hB2, 8, rA2[1], sc, rB2);
  selectStep(hC1, 4, rB1[1], sc, rC1);
  selectStep(hC2, 4, rB2[1], sc, rC2);
  unsigned K1 = (rA1[0] << 21) | (rB1[0] << 10) | rC1[0];
  unsigned K2 = (rA2[0] << 21) | (rB2[0] << 10) | rC2[0];
  if (threadIdx.x == 0) { needs[0] = rC1[1]; needs[1] = rC2[1]; }
  float s0 = 0.f, s1 = 0.f, s2 = 0.f, s3 = 0.f;
  for (int i = blockIdx.x * blockDim.x + threadIdx.x; i < N;
       i += gridDim.x * blockDim.x) {
    float f1 = l1[i], f2 = l2[i];
    unsigned k1 = keyOf(f1), k2 = keyOf(f2);
    if (k2 < K2) {
      s0 += f1;  // loss_1_update: loss_1 on net-2's selected set
    } else if (k2 == K2) {
      unsigned p = atomicAdd(&tc[1], 1u);
      if (p < MAXT) { tIdx2[p] = i; tVal2[p] = f1; }
    }
    if (k1 < K1) {
      s1 += f2;  // loss_2_update: loss_2 on net-1's selected set
    } else if (k1 == K1) {
      unsigned p = atomicAdd(&tc[0], 1u);
      if (p < MAXT) { tIdx1[p] = i; tVal1[p] = f2; }
    }
    s2 += f1;
    s3 += f2;
  }
  s0 = waveSum(s0); s1 = waveSum(s1); s2 = waveSum(s2); s3 = waveSum(s3);
  __shared__ float red[4][4];
  int wid = threadIdx.x >> 6, lane = threadIdx.x & 63;
  if (lane == 0) {
    red[wid][0] = s0; red[wid][1] = s1; red[wid][2] = s2; red[wid][3] = s3;
  }
  __syncthreads();
  if (threadIdx.x == 0) {
    for (int q = 0; q < 4; ++q)
      partials[blockIdx.x * 4 + q] =
          red[0][q] + red[1][q] + red[2][q] + red[3][q];
  }
}

// Reduce partials; resolve ties deterministically: among equal keys the
// stable argsort selects the smallest indices. Each tied element's rank by
// index is unique -> slot[rank] = value; sum slots 0..need-1 sequentially.
__global__ __launch_bounds__(256) void final_kernel(
    const float* __restrict__ partials, const int* __restrict__ numKeep,
    const unsigned* __restrict__ needs, const unsigned* __restrict__ tc,
    const int* __restrict__ tIdx1, const float* __restrict__ tVal1,
    const int* __restrict__ tIdx2, const float* __restrict__ tVal2,
    float* __restrict__ out, int N, int nBlocks) {
  __shared__ float slots[MAXT];
  __shared__ float red[4][4];
  __shared__ float tieSum[2];
  int t = threadIdx.x;
  float s0 = 0.f, s1 = 0.f, s2 = 0.f, s3 = 0.f;
  for (int j = t; j < nBlocks; j += 256) {
    s0 += partials[j * 4 + 0];
    s1 += partials[j * 4 + 1];
    s2 += partials[j * 4 + 2];
    s3 += partials[j * 4 + 3];
  }
  s0 = waveSum(s0); s1 = waveSum(s1); s2 = waveSum(s2); s3 = waveSum(s3);
  int wid = t >> 6, lane = t & 63;
  if (lane == 0) {
    red[wid][0] = s0; red[wid][1] = s1; red[wid][2] = s2; red[wid][3] = s3;
  }
  // ties for array a (0: ties of l1 -> contribute tVal1=f2 to s1;
  //                   1: ties of l2 -> contribute tVal2=f1 to s0)
  for (int a = 0; a < 2; ++a) {
    const int* ti = a ? tIdx2 : tIdx1;
    const float* tv = a ? tVal2 : tVal1;
    int T = min((int)tc[a], MAXT);
    int need = min((int)needs[a], T);
    __syncthreads();
    for (int j = t; j < T; j += 256) {
      int idx = ti[j];
      int rk = 0;
      for (int m = 0; m < T; ++m) rk += (ti[m] < idx) ? 1 : 0;
      if (rk < need) slots[rk] = tv[j];
    }
    __syncthreads();
    if (t == 0) {
      float s = 0.f;
      for (int j = 0; j < need; ++j) s += slots[j];
      tieSum[a] = s;
    }
  }
  __syncthreads();
  if (t == 0) {
    float a0 = red[0][0] + red[1][0] + red[2][0] + red[3][0] + tieSum[1];
    float a1 = red[0][1] + red[1][1] + red[2][1] + red[3][1] + tieSum[0];
    float a2 = red[0][2] + red[1][2] + red[2][2] + red[3][2];
    float a3 = red[0][3] + red[1][3] + red[2][3] + red[3][3];
    float k = (float)(*numKeep);
    out[0] = a0 / k;
    out[1] = a1 / k;
    out[2] = a2 / (float)N;
    out[3] = a3 / (float)N;
  }
}

extern "C" void kernel_launch(void* const* d_in, const int* in_sizes, int n_in,
                              void* d_out, int out_size, void* d_ws,
                              size_t ws_size, hipStream_t stream) {
  const float* y1 = (const float*)d_in[0];
  const float* y2 = (const float*)d_in[1];
  const int* tgt = (const int*)d_in[2];
  const int* numKeep = (const int*)d_in[3];
  int N = in_sizes[2];  // 65536 (C = 1000 hardcoded in ce_kernel)
  float* out = (float*)d_out;

  // workspace layout
  float* l1 = (float*)d_ws;                // N fp32
  float* l2 = l1 + N;                      // N fp32
  unsigned* hA1 = (unsigned*)(l2 + N);     // 2048
  unsigned* hA2 = hA1 + 2048;              // 2048
  unsigned* hB1 = hA2 + 2048;              // 2048
  unsigned* hB2 = hB1 + 2048;              // 2048
  unsigned* hC1 = hB2 + 2048;              // 1024
  unsigned* hC2 = hC1 + 1024;              // 1024
  unsigned* tc = hC2 + 1024;               // 2
  unsigned* needs = tc + 2;                // 2
  int* tIdx1 = (int*)(needs + 2);          // MAXT
  float* tVal1 = (float*)(tIdx1 + MAXT);   // MAXT
  int* tIdx2 = (int*)(tVal1 + MAXT);       // MAXT
  float* tVal2 = (float*)(tIdx2 + MAXT);   // MAXT
  float* partials = (float*)(tVal2 + MAXT);  // 256*4

  init_kernel<<<1, 256, 0, stream>>>(hA1, tc);
  ce_kernel<<<(N + 3) / 4, 256, 0, stream>>>(y1, y2, tgt, l1, l2, N);
  histA_kernel<<<256, 256, 0, stream>>>(l1, l2, hA1, hA2, N);
  histB_kernel<<<256, 256, 0, stream>>>(l1, l2, hA1, hA2, hB1, hB2, numKeep, N);
  histC_kernel<<<256, 256, 0, stream>>>(l1, l2, hA1, hA2, hB1, hB2, hC1, hC2,
                                        numKeep, N);
  partial_kernel<<<256, 256, 0, stream>>>(l1, l2, hA1, hA2, hB1, hB2, hC1, hC2,
                                          numKeep, needs, tc, tIdx1, tVal1,
                                          tIdx2, tVal2, partials, N);
  final_kernel<<<1, 256, 0, stream>>>(partials, numKeep, needs, tc, tIdx1,
                                      tVal1, tIdx2, tVal2, out, N, 256);
}